// Round 1
// 408.606 us; speedup vs baseline: 1.0316x; 1.0316x over previous
//
#include <hip/hip_runtime.h>
#include <stdint.h>

#define N_NODES 100000
#define N_EDGES 1600000
#define F 128
#define CBN 512                    // nodes per coarse bucket
#define NCBK 196                   // ceil(N_NODES/CBN)
#define CHUNK 4096                 // edges per binA/bhist block
#define BUFCAP 10240               // binB LDS edge buffer (mean 8192 + ~22 sigma)

typedef _Float16 f16;
typedef _Float16 f16x4 __attribute__((ext_vector_type(4)));
typedef _Float16 f16x8 __attribute__((ext_vector_type(8)));
typedef float f32x4 __attribute__((ext_vector_type(4)));

// edge pack: (src << 15) | (fp16 bits of w, sign bit dropped — w in [0,1))
__device__ inline float unpackw(unsigned int p) {
    unsigned short b = (unsigned short)(p & 0x7FFF);
    return (float)__builtin_bit_cast(f16, b);
}

// ---------------- R14 front-end: 196-bucket histogram only ----------------
// (R13's 100k-node histogram + 3-phase scan deleted: binB now derives per-node
// row[] itself from its bucket's edges in LDS.)

__global__ void k_zero0(int* bktcnt) {
    int i = threadIdx.x;
    if (i < NCBK) bktcnt[i] = 0;
}

// LDS histogram of dst>>9 per 4096-edge chunk, one global atomic per (block,bucket)
__launch_bounds__(256)
__global__ void k_bhist(const int* __restrict__ ei, int* __restrict__ bktcnt, int e) {
    __shared__ int h[NCBK];
    int tid = threadIdx.x;
    if (tid < NCBK) h[tid] = 0;
    __syncthreads();
    int base = blockIdx.x * CHUNK;
    int cnt = min(CHUNK, e - base);
    const int* dst = ei + N_EDGES + base;
    if (cnt == CHUNK) {
        const int4* d4 = (const int4*)dst;
#pragma unroll
        for (int k = 0; k < 4; k++) {
            int4 v = d4[tid + k * 256];
            atomicAdd(&h[v.x >> 9], 1);
            atomicAdd(&h[v.y >> 9], 1);
            atomicAdd(&h[v.z >> 9], 1);
            atomicAdd(&h[v.w >> 9], 1);
        }
    } else {
        for (int i = tid; i < cnt; i += 256)
            atomicAdd(&h[dst[i] >> 9], 1);
    }
    __syncthreads();
    if (tid < NCBK && h[tid]) atomicAdd(&bktcnt[tid], h[tid]);
}

// one block: exclusive scan of 196 bucket counts -> gbase[197], init gcur, row[N]
__launch_bounds__(256)
__global__ void k_bktscan(const int* __restrict__ bktcnt, int* __restrict__ gbase,
                          int* __restrict__ gcur, int* __restrict__ row) {
    __shared__ int ls[256];
    int tid = threadIdx.x;
    int v = (tid < NCBK) ? bktcnt[tid] : 0;
    ls[tid] = v;
    __syncthreads();
    for (int off = 1; off < 256; off <<= 1) {
        int t = (tid >= off) ? ls[tid - off] : 0;
        __syncthreads();
        ls[tid] += t;
        __syncthreads();
    }
    int ex = ls[tid] - v;
    if (tid < NCBK) { gbase[tid] = ex; gcur[tid] = ex; }
    if (tid == NCBK) gbase[NCBK] = N_EDGES;
    if (tid == 0) row[N_NODES] = N_EDGES;
}

// ---------------- LDS write-combining binner (R13, proven) ----------------
// Measured R9-R12: scattered/temporally-sparse partial-line writes cost ~5x
// write amplification. binA converts per-edge scatter into per-(block,bin)
// contiguous runs claimed with one atomic each.

__launch_bounds__(256)
__global__ void k_binA(const int* __restrict__ ei, const float* __restrict__ w,
                       int* __restrict__ gcur, int2* __restrict__ stage, int e) {
    __shared__ int hist[256];
    __shared__ int bst[257];
    __shared__ int gb[256];
    __shared__ int ls[256];
    __shared__ int rec[CHUNK];
    __shared__ int meta[CHUNK];
    int tid = threadIdx.x;
    int base = blockIdx.x * CHUNK;
    int cnt = min(CHUNK, e - base);
    hist[tid] = 0;
    __syncthreads();

    int ew_[16], mr_[16];
    int nloc = 0;
    if (cnt == CHUNK) {
#pragma unroll
        for (int k = 0; k < 16; k++) {
            int i = base + tid + k * 256;
            int s = ei[i];
            int d = ei[N_EDGES + i];
            f16 hw = (f16)w[i];
            unsigned short wb = __builtin_bit_cast(unsigned short, hw);
            ew_[k] = (int)(((unsigned int)s << 15) | (wb & 0x7FFF));
            int cb = d >> 9;
            int local = d & (CBN - 1);
            int r = atomicAdd(&hist[cb], 1);
            mr_[k] = (cb << 22) | (local << 13) | r;   // cb:8 local:9 r:13
        }
        nloc = 16;
    } else {
        for (int i = tid; i < cnt; i += 256) {
            int s = ei[base + i];
            int d = ei[N_EDGES + base + i];
            f16 hw = (f16)w[base + i];
            unsigned short wb = __builtin_bit_cast(unsigned short, hw);
            ew_[nloc] = (int)(((unsigned int)s << 15) | (wb & 0x7FFF));
            int cb = d >> 9;
            int local = d & (CBN - 1);
            int r = atomicAdd(&hist[cb], 1);
            mr_[nloc] = (cb << 22) | (local << 13) | r;
            nloc++;
        }
    }
    __syncthreads();
    int v = hist[tid];
    ls[tid] = v;
    __syncthreads();
    for (int off = 1; off < 256; off <<= 1) {
        int t = (tid >= off) ? ls[tid - off] : 0;
        __syncthreads();
        ls[tid] += t;
        __syncthreads();
    }
    bst[tid] = ls[tid] - v;
    if (tid == 255) bst[256] = ls[255];
    __syncthreads();
    for (int k = 0; k < nloc; k++) {
        int m = mr_[k];
        int cb = m >> 22;
        int pos = bst[cb] + (m & 0x1FFF);
        rec[pos] = ew_[k];
        meta[pos] = (cb << 9) | ((m >> 13) & 0x1FF);
    }
    __syncthreads();
    if (tid < NCBK) {
        int c = bst[tid + 1] - bst[tid];
        gb[tid] = c ? atomicAdd(&gcur[tid], c) : 0;
    }
    __syncthreads();
    for (int j = tid; j < cnt; j += 256) {
        int m = meta[j];
        int cb = m >> 9;
        stage[gb[cb] + (j - bst[cb])] = make_int2(m & 511, rec[j]);
    }
}

// binB: one block per coarse bucket. Derives per-node row[] itself:
// pass1 count locals -> LDS scan -> row write; pass2 permute to CSR in LDS;
// coalesced final write + fused dinv.
__launch_bounds__(256)
__global__ void k_binB(const int2* __restrict__ stage, const int* __restrict__ gbase,
                       unsigned int* __restrict__ edges, int* __restrict__ row,
                       float* __restrict__ dinv) {
    __shared__ int cnt[CBN];
    __shared__ int ex[CBN + 1];
    __shared__ int cur[CBN];
    __shared__ int ls[256];
    __shared__ unsigned int buf[BUFCAP];
    int tid = threadIdx.x;
    int cb = blockIdx.x;
    int n0 = cb * CBN;
    int nn = min(CBN, N_NODES - n0);
    int base = gbase[cb];
    int hi = gbase[cb + 1];
    cnt[tid] = 0;
    cnt[tid + 256] = 0;
    __syncthreads();
    // pass 1: local histogram
    for (int j = base + tid; j < hi; j += 256)
        atomicAdd(&cnt[stage[j].x], 1);
    __syncthreads();
    // exclusive scan of 512 (2 per thread)
    int a = cnt[2 * tid], b = cnt[2 * tid + 1];
    int s = a + b;
    ls[tid] = s;
    __syncthreads();
    for (int off = 1; off < 256; off <<= 1) {
        int t = (tid >= off) ? ls[tid - off] : 0;
        __syncthreads();
        ls[tid] += t;
        __syncthreads();
    }
    int bx = ls[tid] - s;
    ex[2 * tid] = bx;
    ex[2 * tid + 1] = bx + a;
    cur[2 * tid] = bx;
    cur[2 * tid + 1] = bx + a;
    if (tid == 255) ex[512] = ls[255];
    __syncthreads();
    // row write (row[n0+nn] is the next block's base; row[N] by k_bktscan)
    for (int l = tid; l < nn; l += 256) row[n0 + l] = base + ex[l];
    // pass 2: permute to CSR order in LDS
    for (int j = base + tid; j < hi; j += 256) {
        int2 r = stage[j];
        int p = atomicAdd(&cur[r.x], 1);
        buf[p] = (unsigned int)r.y;
    }
    __syncthreads();
    int range = hi - base;
    for (int j = tid; j < range; j += 256)
        edges[base + j] = buf[j];
    // fused dinv: deg = 1 + sum w over the node's CSR slice (in LDS)
    for (int l = tid; l < nn; l += 256) {
        int lo = ex[l];
        int h2 = ex[l + 1];
        float sm = 1.0f;
        for (int j = lo; j < h2; j++) sm += unpackw(buf[j]);
        dinv[n0 + l] = rsqrtf(sm);
    }
}

// ---------------- fp32 -> fp16 conversions ----------------

__global__ void k_cvt(const float* __restrict__ X, f16* __restrict__ Y, int n8) {
    int i = blockIdx.x * blockDim.x + threadIdx.x;
    if (i < n8) {
        float4 a = ((const float4*)X)[i * 2];
        float4 b = ((const float4*)X)[i * 2 + 1];
        f16x8 o;
        o[0] = (f16)a.x; o[1] = (f16)a.y; o[2] = (f16)a.z; o[3] = (f16)a.w;
        o[4] = (f16)b.x; o[5] = (f16)b.y; o[6] = (f16)b.z; o[7] = (f16)b.w;
        ((f16x8*)Y)[i] = o;
    }
}

__global__ void k_wt2(const float* __restrict__ Wa, const float* __restrict__ Wb,
                      f16* __restrict__ Wta, f16* __restrict__ Wtb) {
    const float* W = blockIdx.x ? Wb : Wa;
    f16* Wt = blockIdx.x ? Wtb : Wta;
    int t = threadIdx.x;
#pragma unroll
    for (int it = 0; it < 64; it++) {
        int idx = t + it * 256;
        int k = idx >> 7, n = idx & 127;
        Wt[n * 128 + k] = (f16)W[idx];
    }
}

// ---------------- fp16 MFMA GEMM, epilogue scales rows by dinv ----------------

#define LDK 136

__launch_bounds__(256, 2)
__global__ void k_gemm16(const f16* __restrict__ A, const f16* __restrict__ Wt,
                         const float* __restrict__ dinv, f16* __restrict__ H, int nrows) {
    __shared__ f16 Ws[128 * LDK];
    int tid = threadIdx.x;
    int r0 = blockIdx.x * 128;
    int wave = tid >> 6;
    int lane = tid & 63;
    int lrow = lane & 15;
    int quad = lane >> 4;

    f16x8 a[2][4];
#pragma unroll
    for (int mt = 0; mt < 2; mt++) {
        int row = r0 + wave * 32 + mt * 16 + lrow;
#pragma unroll
        for (int kc = 0; kc < 4; kc++) {
            if (row < nrows)
                a[mt][kc] = *(const f16x8*)&A[(size_t)row * F + kc * 32 + quad * 8];
            else
                a[mt][kc] = (f16x8){};
        }
    }
#pragma unroll
    for (int it = 0; it < 8; it++) {
        int c = tid + it * 256;
        int rw = c >> 4;
        int off = (c & 15) * 8;
        *(f16x8*)&Ws[rw * LDK + off] = *(const f16x8*)&Wt[rw * 128 + off];
    }
    __syncthreads();

    f32x4 acc[2][8] = {};
#pragma unroll
    for (int kc = 0; kc < 4; kc++) {
        f16x8 b[8];
#pragma unroll
        for (int nt = 0; nt < 8; nt++)
            b[nt] = *(const f16x8*)&Ws[(nt * 16 + lrow) * LDK + kc * 32 + quad * 8];
#pragma unroll
        for (int nt = 0; nt < 8; nt++) {
            acc[0][nt] = __builtin_amdgcn_mfma_f32_16x16x32_f16(a[0][kc], b[nt], acc[0][nt], 0, 0, 0);
            acc[1][nt] = __builtin_amdgcn_mfma_f32_16x16x32_f16(a[1][kc], b[nt], acc[1][nt], 0, 0, 0);
        }
    }
    __syncthreads();
#pragma unroll
    for (int mt = 0; mt < 2; mt++) {
#pragma unroll
        for (int r = 0; r < 4; r++) {
            int lr = wave * 32 + mt * 16 + quad * 4 + r;
            int grow = r0 + lr;
            float dv = (grow < nrows) ? dinv[grow] : 0.f;
#pragma unroll
            for (int nt = 0; nt < 8; nt++)
                Ws[lr * 132 + nt * 16 + lrow] = (f16)(acc[mt][nt][r] * dv);
        }
    }
    __syncthreads();
#pragma unroll
    for (int it = 0; it < 8; it++) {
        int c = it * 256 + tid;
        int rw = c >> 4;
        int col = (c & 15) * 8;
        int grow = r0 + rw;
        if (grow < nrows)
            *(f16x8*)&H[(size_t)grow * F + col] = *(const f16x8*)&Ws[rw * 132 + col];
    }
}

// ---------------- aggregation (R15): one node per 16-lane quarter ----------------
// R14 used one wave per node: 100k waves each paying prologue + cross-quarter
// shfl reduce + a 75%-masked epilogue — per-wave fixed VALU cost dominated
// (VALUBusy 54% while the edge loop itself is ~6 µs of issue). R15: 4 nodes per
// wave (16/block), features stay lane-local (no reduce), epilogue all-lanes,
// 4-deep gather unroll (16 outstanding 16B gathers/wave). Tail via index clamp
// + zero weight (clamped slot re-reads slot-0's row -> L1 hit).

__launch_bounds__(256)
__global__ void k_agg(const f16* __restrict__ H16, const int* __restrict__ row,
                      const unsigned int* __restrict__ edges,
                      const float* __restrict__ dinv, const float* __restrict__ bias,
                      f16* __restrict__ out, int n) {
    int node = blockIdx.x * 16 + (threadIdx.x >> 4);
    if (node >= n) return;
    int sub = threadIdx.x & 15;
    int beg = row[node], end = row[node + 1];
    float acc0[8] = {}, acc1[8] = {}, acc2[8] = {}, acc3[8] = {};
    int em1 = end - 1;
    for (int t = beg; t < end; t += 4) {
        int i1 = min(t + 1, em1);
        int i2 = min(t + 2, em1);
        int i3 = min(t + 3, em1);
        unsigned int e0 = edges[t];
        unsigned int e1 = edges[i1];
        unsigned int e2 = edges[i2];
        unsigned int e3 = edges[i3];
        float w0 = unpackw(e0);
        float w1 = (t + 1 < end) ? unpackw(e1) : 0.f;
        float w2 = (t + 2 < end) ? unpackw(e2) : 0.f;
        float w3 = (t + 3 < end) ? unpackw(e3) : 0.f;
        f16x8 v0 = *(const f16x8*)&H16[(size_t)(e0 >> 15) * F + sub * 8];
        f16x8 v1 = *(const f16x8*)&H16[(size_t)(e1 >> 15) * F + sub * 8];
        f16x8 v2 = *(const f16x8*)&H16[(size_t)(e2 >> 15) * F + sub * 8];
        f16x8 v3 = *(const f16x8*)&H16[(size_t)(e3 >> 15) * F + sub * 8];
#pragma unroll
        for (int j = 0; j < 8; j++) {
            acc0[j] = fmaf(w0, (float)v0[j], acc0[j]);
            acc1[j] = fmaf(w1, (float)v1[j], acc1[j]);
            acc2[j] = fmaf(w2, (float)v2[j], acc2[j]);
            acc3[j] = fmaf(w3, (float)v3[j], acc3[j]);
        }
    }
    float dd = dinv[node];
    f16x8 h = *(const f16x8*)&H16[(size_t)node * F + sub * 8];
    float4 b0 = *(const float4*)&bias[sub * 8];
    float4 b1 = *(const float4*)&bias[sub * 8 + 4];
    float bb[8] = {b0.x, b0.y, b0.z, b0.w, b1.x, b1.y, b1.z, b1.w};
    f16x8 o;
#pragma unroll
    for (int j = 0; j < 8; j++) {
        float a = acc0[j] + acc1[j] + acc2[j] + acc3[j] + (float)h[j];
        o[j] = (f16)fmaxf(fmaf(dd, a, bb[j]), 0.f);
    }
    *(f16x8*)&out[(size_t)node * F + sub * 8] = o;
}

// agg3 fused with final dot: s'[node] = dinv[node] * ( relu(agg3) . Wfin )
__launch_bounds__(256)
__global__ void k_agg_dot(const f16* __restrict__ H16, const int* __restrict__ row,
                          const unsigned int* __restrict__ edges,
                          const float* __restrict__ dinv, const float* __restrict__ bias,
                          const float* __restrict__ Wf, float* __restrict__ sout, int n) {
    int node = blockIdx.x * 16 + (threadIdx.x >> 4);
    if (node >= n) return;
    int sub = threadIdx.x & 15;
    int beg = row[node], end = row[node + 1];
    float acc0[8] = {}, acc1[8] = {}, acc2[8] = {}, acc3[8] = {};
    int em1 = end - 1;
    for (int t = beg; t < end; t += 4) {
        int i1 = min(t + 1, em1);
        int i2 = min(t + 2, em1);
        int i3 = min(t + 3, em1);
        unsigned int e0 = edges[t];
        unsigned int e1 = edges[i1];
        unsigned int e2 = edges[i2];
        unsigned int e3 = edges[i3];
        float w0 = unpackw(e0);
        float w1 = (t + 1 < end) ? unpackw(e1) : 0.f;
        float w2 = (t + 2 < end) ? unpackw(e2) : 0.f;
        float w3 = (t + 3 < end) ? unpackw(e3) : 0.f;
        f16x8 v0 = *(const f16x8*)&H16[(size_t)(e0 >> 15) * F + sub * 8];
        f16x8 v1 = *(const f16x8*)&H16[(size_t)(e1 >> 15) * F + sub * 8];
        f16x8 v2 = *(const f16x8*)&H16[(size_t)(e2 >> 15) * F + sub * 8];
        f16x8 v3 = *(const f16x8*)&H16[(size_t)(e3 >> 15) * F + sub * 8];
#pragma unroll
        for (int j = 0; j < 8; j++) {
            acc0[j] = fmaf(w0, (float)v0[j], acc0[j]);
            acc1[j] = fmaf(w1, (float)v1[j], acc1[j]);
            acc2[j] = fmaf(w2, (float)v2[j], acc2[j]);
            acc3[j] = fmaf(w3, (float)v3[j], acc3[j]);
        }
    }
    float dd = dinv[node];
    f16x8 h = *(const f16x8*)&H16[(size_t)node * F + sub * 8];
    float4 b0 = *(const float4*)&bias[sub * 8];
    float4 b1 = *(const float4*)&bias[sub * 8 + 4];
    float bb[8] = {b0.x, b0.y, b0.z, b0.w, b1.x, b1.y, b1.z, b1.w};
    float4 w0v = *(const float4*)&Wf[sub * 8];
    float4 w1v = *(const float4*)&Wf[sub * 8 + 4];
    float ww[8] = {w0v.x, w0v.y, w0v.z, w0v.w, w1v.x, w1v.y, w1v.z, w1v.w};
    float p = 0.f;
#pragma unroll
    for (int j = 0; j < 8; j++) {
        float a = acc0[j] + acc1[j] + acc2[j] + acc3[j] + (float)h[j];
        p += fmaxf(fmaf(dd, a, bb[j]), 0.f) * ww[j];
    }
    p += __shfl_xor(p, 8, 64);
    p += __shfl_xor(p, 4, 64);
    p += __shfl_xor(p, 2, 64);
    p += __shfl_xor(p, 1, 64);
    if (sub == 0) sout[node] = dd * p;
}

__global__ void k_aggs(const float* __restrict__ s, const int* __restrict__ row,
                       const unsigned int* __restrict__ edges,
                       const float* __restrict__ dinv, const float* __restrict__ bf,
                       float* __restrict__ out, int n) {
    int i = blockIdx.x * blockDim.x + threadIdx.x;
    if (i >= n) return;
    float dd = dinv[i];
    float ae = s[i];
    int beg = row[i], end = row[i + 1];
    for (int j = beg; j < end; j++) {
        unsigned int p = edges[j];
        ae = fmaf(unpackw(p), s[p >> 15], ae);
    }
    out[i] = fmaf(dd, ae, bf[0]);
}

// ---------------- host launch ----------------

extern "C" void kernel_launch(void* const* d_in, const int* in_sizes, int n_in,
                              void* d_out, int out_size, void* d_ws, size_t ws_size,
                              hipStream_t stream) {
    const float* x    = (const float*)d_in[0];
    const int*   ei   = (const int*)d_in[1];
    const float* ew   = (const float*)d_in[2];
    const float* Win  = (const float*)d_in[3];
    const float* bin  = (const float*)d_in[4];
    const float* Wmid = (const float*)d_in[5];
    const float* bmid = (const float*)d_in[6];
    const float* Wfin = (const float*)d_in[7];
    const float* bfin = (const float*)d_in[8];
    float* out = (float*)d_out;

    char* ws = (char*)d_ws;
    size_t off = 0;
    auto alloc = [&](size_t bytes) -> char* {
        char* p = ws + off;
        off = (off + bytes + 255) & ~(size_t)255;
        return p;
    };
    float* dinv  = (float*)alloc((size_t)N_NODES * 4);
    int*   row   = (int*)alloc((size_t)(N_NODES + 1) * 4);
    unsigned int* edges = (unsigned int*)alloc((size_t)N_EDGES * 4);
    int*   bktcnt = (int*)alloc(256 * 4);
    int*   gbase  = (int*)alloc(256 * 4);
    int*   gcur   = (int*)alloc(256 * 4);
    f16*   wtin  = (f16*)alloc(128 * 128 * 2);
    f16*   wtmid = (f16*)alloc(128 * 128 * 2);
    f16*   H16   = (f16*)alloc((size_t)N_NODES * F * 2);   // gemm out (dinv-scaled) / agg in
    f16*   AB16  = (f16*)alloc((size_t)N_NODES * F * 2);   // x16 -> agg out chain
    // stage aliased into H16 (consumed by binB before gemm1 writes H16):
    int2* stage = (int2*)H16;                               // 12.8 MB
    float* sbuf = (float*)AB16;  // aliased: consumed by gemm3 before agg_dot writes

    dim3 b256(256);
    int gN = (N_NODES + 255) / 256;
    int gW = (N_NODES + 15) / 16;
    int gG = (N_NODES + 127) / 128;
    int n8 = N_NODES * F / 8;
    int gC = (n8 + 255) / 256;
    int gA = (N_EDGES + CHUNK - 1) / CHUNK;   // 391

    hipLaunchKernelGGL(k_zero0, dim3(1), b256, 0, stream, bktcnt);
    hipLaunchKernelGGL(k_bhist, dim3(gA), b256, 0, stream, ei, bktcnt, N_EDGES);
    hipLaunchKernelGGL(k_bktscan, dim3(1), b256, 0, stream, bktcnt, gbase, gcur, row);
    hipLaunchKernelGGL(k_binA, dim3(gA), b256, 0, stream, ei, ew, gcur, stage, N_EDGES);
    hipLaunchKernelGGL(k_binB, dim3(NCBK), b256, 0, stream, stage, gbase, edges, row, dinv);
    hipLaunchKernelGGL(k_cvt, dim3(gC), b256, 0, stream, x, AB16, n8);
    hipLaunchKernelGGL(k_wt2, dim3(2), b256, 0, stream, Win, Wmid, wtin, wtmid);

    hipLaunchKernelGGL(k_gemm16, dim3(gG), b256, 0, stream, AB16, wtin, dinv, H16, N_NODES);
    hipLaunchKernelGGL(k_agg, dim3(gW), b256, 0, stream, H16, row, edges, dinv, bin, AB16, N_NODES);
    hipLaunchKernelGGL(k_gemm16, dim3(gG), b256, 0, stream, AB16, wtmid, dinv, H16, N_NODES);
    hipLaunchKernelGGL(k_agg, dim3(gW), b256, 0, stream, H16, row, edges, dinv, bmid, AB16, N_NODES);
    hipLaunchKernelGGL(k_gemm16, dim3(gG), b256, 0, stream, AB16, wtmid, dinv, H16, N_NODES);
    hipLaunchKernelGGL(k_agg_dot, dim3(gW), b256, 0, stream, H16, row, edges, dinv, bmid, Wfin, sbuf, N_NODES);
    hipLaunchKernelGGL(k_aggs, dim3(gN), b256, 0, stream, sbuf, row, edges, dinv, bfin, out, N_NODES);
}